// Round 11
// baseline (389.465 us; speedup 1.0000x reference)
//
#include <hip/hip_runtime.h>
#include <hip/hip_bf16.h>

typedef __bf16 bf16;
typedef __bf16 bf16x4 __attribute__((ext_vector_type(4)));
typedef __bf16 bf16x8 __attribute__((ext_vector_type(8)));
typedef float f32x4 __attribute__((ext_vector_type(4)));

static __device__ __forceinline__ f32x4 mfma16(bf16x8 a, bf16x8 b, f32x4 c) {
  return __builtin_amdgcn_mfma_f32_16x16x32_bf16(a, b, c, 0, 0, 0);
}

static __device__ __forceinline__ bf16x8 cvt8(const float* p) {
  f32x4 a0 = *(const f32x4*)p;
  f32x4 a1 = *(const f32x4*)(p + 4);
  bf16x8 r;
#pragma unroll
  for (int j = 0; j < 4; ++j) { r[j] = (bf16)a0[j]; r[4 + j] = (bf16)a1[j]; }
  return r;
}

// ---------------------------------------------------------------------------
// prep_wt: Wt[c][k] = W*(k,c). One block per c -> contiguous 512B writes.
// ---------------------------------------------------------------------------
__global__ void prep_wt(const float* __restrict__ Wq, const float* __restrict__ Wk,
                        const float* __restrict__ Wv, bf16* __restrict__ Wt) {
  int c = blockIdx.x;   // 0..319
  int k = threadIdx.x;  // 0..255
  float v;
  if (c < 32)       v = Wq[k * 32 + c];
  else if (c < 64)  v = Wk[k * 32 + (c - 32)];
  else              v = Wv[k * 256 + (c - 64)];
  Wt[c * 256 + k] = (bf16)v;
}

// ---------------------------------------------------------------------------
// qkv_gemm: one block per 64-row tile; x A-frags loaded once into registers,
// looped over all 5 column tiles. V epilogue via LDS transpose.
// ---------------------------------------------------------------------------
__global__ __launch_bounds__(256) void qkv_gemm(
    const float* __restrict__ x, const bf16* __restrict__ Wt,
    const float* __restrict__ bq, const float* __restrict__ bk,
    const float* __restrict__ bv,
    bf16* __restrict__ Qd, bf16* __restrict__ Kd, bf16* __restrict__ Vt) {
  __shared__ __align__(16) bf16 tile[64 * 72];
  int tid = threadIdx.x;
  int lane = tid & 63, w = tid >> 6;
  int lw = lane & 15, qq = lane >> 4;
  int r0 = blockIdx.x * 64;
  int bb = r0 >> 12, n0 = r0 & 4095;

  const float* arow = x + (size_t)(r0 + 16 * w + lw) * 256;
  bf16x8 a[8];
#pragma unroll
  for (int kc = 0; kc < 8; ++kc) a[kc] = cvt8(arow + kc * 32 + qq * 8);

  for (int c0 = 0; c0 < 320; c0 += 64) {
    f32x4 acc[4] = {};
#pragma unroll
    for (int kc = 0; kc < 8; ++kc)
#pragma unroll
      for (int t = 0; t < 4; ++t) {
        bf16x8 b = *(const bf16x8*)(Wt + (size_t)(c0 + 16 * t + lw) * 256 + kc * 32 + qq * 8);
        acc[t] = mfma16(a[kc], b, acc[t]);
      }
    // C/D: col = lane&15, row = (lane>>4)*4 + i
    if (c0 == 0) {
#pragma unroll
      for (int t = 0; t < 4; ++t) {
        int c = 16 * t + lw;
        float bias = (c < 32) ? bq[c] : bk[c - 32];
#pragma unroll
        for (int i = 0; i < 4; ++i) {
          int n = n0 + 16 * w + 4 * qq + i;
          bf16 hv = (bf16)(acc[t][i] + bias);
          if (c < 32) Qd[((size_t)(bb << 12) + n) * 32 + c] = hv;
          else        Kd[((size_t)(bb << 12) + n) * 32 + (c - 32)] = hv;
        }
      }
    } else {
#pragma unroll
      for (int t = 0; t < 4; ++t) {
        int cl = 16 * t + lw;
        float bias = bv[c0 - 64 + cl];
#pragma unroll
        for (int i = 0; i < 4; ++i)
          tile[cl * 72 + 16 * w + 4 * qq + i] = (bf16)(acc[t][i] + bias);
      }
      __syncthreads();
      int nl = tid & 63;
#pragma unroll
      for (int it = 0; it < 16; ++it) {
        int cl = 4 * it + w;  // wave-uniform col -> 128B contiguous stores
        Vt[((size_t)bb * 256 + (c0 - 64) + cl) * 4096 + n0 + nl] = tile[cl * 72 + nl];
      }
      __syncthreads();
    }
  }
}

// ---------------------------------------------------------------------------
// flash_attn: BARRIER-FREE K-loop. 512 threads (8 waves), grid (batch, 64).
// Wave (wr = w&3, g = w>>2): q-rows [r0+16wr, +16), ALL 256 channels,
// kv half [2048g, +2048), 32 iterations of 64 kv.
//  - S^T = mfma(kf, qf): C-layout col=q, row=kv (per-wave private).
//  - exp + in-register C->A transpose via 8 shfls (qq-quad redistribution).
//  - PV: V B-frags straight from Vt (ch-major, k-contiguous); o[16] f32x4.
//  - Deferred softmax (no max; scores bounded) => kv-half partials add.
// ONE __syncthreads total (g-merge at end). K dbuf with literal names.
// ---------------------------------------------------------------------------
__global__ __launch_bounds__(512, 2) void flash_attn(
    const bf16* __restrict__ Qd, const bf16* __restrict__ Kd,
    const bf16* __restrict__ Vt, const float* __restrict__ x,
    const float* __restrict__ gamma, float* __restrict__ out) {
  __shared__ __align__(16) float obuf[4][16][256];  // 64 KB merge staging
  __shared__ __align__(16) float lsum2[2][64];

  int tid = threadIdx.x;
  int lane = tid & 63, w = tid >> 6;   // 8 waves
  int lw = lane & 15, qq = lane >> 4;
  int wr = w & 3, g = w >> 2;
  int bb = blockIdx.x;                 // batch fastest -> XCD L2 locality
  int r0 = blockIdx.y * 64;
  int nbase = g * 2048;

  const bf16* Qb = Qd + ((size_t)bb << 12) * 32;
  const bf16* Kb = Kd + ((size_t)bb << 12) * 32;
  const bf16* Vb = Vt + (size_t)bb * 256 * 4096;

  // Q as B-frag: B[n=lw -> q row][k=8qq+j -> d]
  bf16x8 qf = *(const bf16x8*)(Qb + (size_t)(r0 + 16 * wr + lw) * 32 + qq * 8);

  f32x4 o[16] = {};       // o[tt][i] = O[q=16wr+4qq+i][ch=16tt+lw]
  float l_acc = 0.f;      // per-lane partial of row q=16wr+lw
  int hi = qq >> 1;
  int srcA = ((qq & 1) << 5) + lw;   // source lane for j=0..3
  int srcB = srcA + 16;              // source lane for j=4..7
  const bf16* vbase = Vb + (size_t)lw * 4096 + qq * 8;

  bf16x8 kA[4], kB[4];
#pragma unroll
  for (int t = 0; t < 4; ++t)
    kA[t] = *(const bf16x8*)(Kb + (size_t)(nbase + 16 * t + lw) * 32 + qq * 8);

#define FA_BODY(JL, KUSE, KPRE)                                                 \
  {                                                                             \
    int jl = (JL);                                                              \
    int n0 = nbase + jl * 64;                                                   \
    int nn = nbase + ((jl + 1) & 31) * 64;                                      \
    f32x4 st[4]; /* S^T: lane holds P[q=lw][kv=16t+4qq+i] */                    \
    _Pragma("unroll") for (int t = 0; t < 4; ++t) {                             \
      f32x4 z = {};                                                             \
      st[t] = mfma16(KUSE[t], qf, z);                                           \
    }                                                                           \
    _Pragma("unroll") for (int t = 0; t < 4; ++t)                               \
      KPRE[t] = *(const bf16x8*)(Kb + (size_t)(nn + 16 * t + lw) * 32 + qq * 8);\
    int pk[4][2];                                                               \
    _Pragma("unroll") for (int t = 0; t < 4; ++t) {                             \
      union { bf16x4 h; int d[2]; } u;                                          \
      _Pragma("unroll") for (int i = 0; i < 4; ++i) {                           \
        float p = __expf(st[t][i]);                                             \
        l_acc += p;                                                             \
        u.h[i] = (bf16)p;                                                       \
      }                                                                         \
      pk[t][0] = u.d[0]; pk[t][1] = u.d[1];                                     \
    }                                                                           \
    /* C->A transpose: dest j = P[q=lw][kv=32kc+8qq+j] */                       \
    union { bf16x8 v; int d[4]; } a0, a1;                                       \
    int s00 = hi ? pk[1][0] : pk[0][0];                                         \
    int s01 = hi ? pk[1][1] : pk[0][1];                                         \
    int s10 = hi ? pk[3][0] : pk[2][0];                                         \
    int s11 = hi ? pk[3][1] : pk[2][1];                                         \
    a0.d[0] = __shfl(s00, srcA, 64); a0.d[1] = __shfl(s01, srcA, 64);           \
    a0.d[2] = __shfl(s00, srcB, 64); a0.d[3] = __shfl(s01, srcB, 64);           \
    a1.d[0] = __shfl(s10, srcA, 64); a1.d[1] = __shfl(s11, srcA, 64);           \
    a1.d[2] = __shfl(s10, srcB, 64); a1.d[3] = __shfl(s11, srcB, 64);           \
    const bf16* vp = vbase + n0;                                                \
    _Pragma("unroll") for (int tt = 0; tt < 16; ++tt) {                         \
      bf16x8 b0 = *(const bf16x8*)(vp + (size_t)tt * 65536);                    \
      bf16x8 b1 = *(const bf16x8*)(vp + (size_t)tt * 65536 + 32);               \
      o[tt] = mfma16(a0.v, b0, o[tt]);                                          \
      o[tt] = mfma16(a1.v, b1, o[tt]);                                          \
    }                                                                           \
  }

  for (int jj = 0; jj < 16; ++jj) {
    FA_BODY(2 * jj,     kA, kB)
    FA_BODY(2 * jj + 1, kB, kA)
  }
#undef FA_BODY

  // ---- merge the two kv-halves ----
  l_acc += __shfl_xor(l_acc, 16, 64);
  l_acc += __shfl_xor(l_acc, 32, 64);
  if (lane < 16) lsum2[g][16 * wr + lane] = l_acc;
  if (g == 1) {
#pragma unroll
    for (int tt = 0; tt < 16; ++tt)
      *(f32x4*)&obuf[wr][tt][lane * 4] = o[tt];
  }
  __syncthreads();

  if (g == 0) {
    float gm = gamma[0];
#pragma unroll
    for (int tt = 0; tt < 16; ++tt)
      o[tt] += *(const f32x4*)&obuf[wr][tt][lane * 4];
    f32x4 la = *(const f32x4*)&lsum2[0][16 * wr + 4 * qq];
    f32x4 lb = *(const f32x4*)&lsum2[1][16 * wr + 4 * qq];
#pragma unroll
    for (int i = 0; i < 4; ++i) {
      float rinv = 1.f / (la[i] + lb[i]);
      int row = r0 + 16 * wr + 4 * qq + i;
      size_t base = (((size_t)bb << 12) + row) * 256;
#pragma unroll
      for (int tt = 0; tt < 16; ++tt) {
        int c = 16 * tt + lw;
        out[base + c] = gm * (o[tt][i] * rinv) + x[base + c];
      }
    }
  }
}

extern "C" void kernel_launch(void* const* d_in, const int* in_sizes, int n_in,
                              void* d_out, int out_size, void* d_ws, size_t ws_size,
                              hipStream_t stream) {
  const float* x     = (const float*)d_in[0];
  const float* Wq    = (const float*)d_in[1];
  const float* bq    = (const float*)d_in[2];
  const float* Wk    = (const float*)d_in[3];
  const float* bk    = (const float*)d_in[4];
  const float* Wv    = (const float*)d_in[5];
  const float* bv    = (const float*)d_in[6];
  const float* gamma = (const float*)d_in[7];
  float* out = (float*)d_out;

  const size_t WT_E = 320 * 256;
  const size_t QK_E = (size_t)4096 * 32;
  const size_t VT_E = (size_t)256 * 4096;
  size_t full_bytes = (WT_E + 4 * 2 * QK_E + 4 * VT_E) * sizeof(bf16);

  bf16* Wt = (bf16*)d_ws;
  prep_wt<<<dim3(320), dim3(256), 0, stream>>>(Wq, Wk, Wv, Wt);

  if (ws_size >= full_bytes) {
    bf16* Qd = Wt + WT_E;
    bf16* Kd = Qd + 4 * QK_E;
    bf16* Vt = Kd + 4 * QK_E;
    qkv_gemm<<<dim3(256), dim3(256), 0, stream>>>(x, Wt, bq, bk, bv, Qd, Kd, Vt);
    flash_attn<<<dim3(4, 64), dim3(512), 0, stream>>>(Qd, Kd, Vt, x, gamma, out);
  } else {
    bf16* Qd = Wt + WT_E;
    bf16* Kd = Qd + QK_E;
    bf16* Vt = Kd + QK_E;
    for (int b = 0; b < 4; ++b) {
      const float* xb = x + (size_t)b * 4096 * 256;
      float* outb = out + (size_t)b * 4096 * 256;
      qkv_gemm<<<dim3(64), dim3(256), 0, stream>>>(xb, Wt, bq, bk, bv, Qd, Kd, Vt);
      flash_attn<<<dim3(1, 64), dim3(512), 0, stream>>>(Qd, Kd, Vt, xb, gamma, outb);
    }
  }
}

// Round 12
// 188.097 us; speedup vs baseline: 2.0706x; 2.0706x over previous
//
#include <hip/hip_runtime.h>
#include <hip/hip_bf16.h>

typedef __bf16 bf16;
typedef __bf16 bf16x8 __attribute__((ext_vector_type(8)));
typedef float f32x4 __attribute__((ext_vector_type(4)));

static __device__ __forceinline__ f32x4 mfma16(bf16x8 a, bf16x8 b, f32x4 c) {
  return __builtin_amdgcn_mfma_f32_16x16x32_bf16(a, b, c, 0, 0, 0);
}

static __device__ __forceinline__ bf16x8 cvt8(const float* p) {
  f32x4 a0 = *(const f32x4*)p;
  f32x4 a1 = *(const f32x4*)(p + 4);
  bf16x8 r;
#pragma unroll
  for (int j = 0; j < 4; ++j) { r[j] = (bf16)a0[j]; r[4 + j] = (bf16)a1[j]; }
  return r;
}

// ---------------------------------------------------------------------------
// prep_wt: Wt[c][k] = W*(k,c). One block per c -> contiguous 512B writes.
// ---------------------------------------------------------------------------
__global__ void prep_wt(const float* __restrict__ Wq, const float* __restrict__ Wk,
                        const float* __restrict__ Wv, bf16* __restrict__ Wt) {
  int c = blockIdx.x;   // 0..319
  int k = threadIdx.x;  // 0..255
  float v;
  if (c < 32)       v = Wq[k * 32 + c];
  else if (c < 64)  v = Wk[k * 32 + (c - 32)];
  else              v = Wv[k * 256 + (c - 64)];
  Wt[c * 256 + k] = (bf16)v;
}

// ---------------------------------------------------------------------------
// qkv_gemm: grid (row-tiles, 5 col-tiles). V epilogue via LDS transpose.
// ---------------------------------------------------------------------------
__global__ __launch_bounds__(256) void qkv_gemm(
    const float* __restrict__ x, const bf16* __restrict__ Wt,
    const float* __restrict__ bq, const float* __restrict__ bk,
    const float* __restrict__ bv,
    bf16* __restrict__ Qd, bf16* __restrict__ Kd, bf16* __restrict__ Vt) {
  __shared__ __align__(16) bf16 tile[64 * 72];
  int tid = threadIdx.x;
  int lane = tid & 63, w = tid >> 6;
  int lw = lane & 15, qq = lane >> 4;
  int r0 = blockIdx.x * 64, c0 = blockIdx.y * 64;
  int bb = r0 >> 12, n0 = r0 & 4095;

  const float* arow = x + (size_t)(r0 + 16 * w + lw) * 256;
  f32x4 acc[4] = {};
#pragma unroll
  for (int kc = 0; kc < 8; ++kc) {
    bf16x8 a = cvt8(arow + kc * 32 + qq * 8);
#pragma unroll
    for (int t = 0; t < 4; ++t) {
      bf16x8 b = *(const bf16x8*)(Wt + (size_t)(c0 + 16 * t + lw) * 256 + kc * 32 + qq * 8);
      acc[t] = mfma16(a, b, acc[t]);
    }
  }
  // C/D: col = lane&15, row = (lane>>4)*4 + i
  if (c0 == 0) {
#pragma unroll
    for (int t = 0; t < 4; ++t) {
      int c = 16 * t + lw;
      float bias = (c < 32) ? bq[c] : bk[c - 32];
#pragma unroll
      for (int i = 0; i < 4; ++i) {
        int n = n0 + 16 * w + 4 * qq + i;
        bf16 hv = (bf16)(acc[t][i] + bias);
        if (c < 32) Qd[((size_t)(bb << 12) + n) * 32 + c] = hv;
        else        Kd[((size_t)(bb << 12) + n) * 32 + (c - 32)] = hv;
      }
    }
  } else {
#pragma unroll
    for (int t = 0; t < 4; ++t) {
      int cl = 16 * t + lw;
      float bias = bv[c0 - 64 + cl];
#pragma unroll
      for (int i = 0; i < 4; ++i)
        tile[cl * 72 + 16 * w + 4 * qq + i] = (bf16)(acc[t][i] + bias);
    }
    __syncthreads();
    int nl = tid & 63;
#pragma unroll
    for (int it = 0; it < 16; ++it) {
      int cl = 4 * it + w;  // wave-uniform col -> 128B contiguous stores
      Vt[((size_t)bb * 256 + (c0 - 64) + cl) * 4096 + n0 + nl] = tile[cl * 72 + nl];
    }
  }
}

// ---------------------------------------------------------------------------
// flash_attn: r9 structure (proven 85us): Br=64, 256 threads (4 waves).
// Wave w: S rows [16w,16w+16) x all 64 cols; PV channels [64w, 64w+64).
// Pl stride 88, deferred l-sum, double-buffered P, 1 barrier/iter, literal
// register-buffer indices.
// NEW (round 12): XCD-residency block swizzle. Grid = 256 linear blocks;
// assuming linear blockID -> XCD round-robin (%8), batch bb = xcd>>1 lives
// on XCDs {2bb, 2bb+1}, so each XCD's 4MB L2 serves ONE batch's KV (2.25MB)
// instead of >=2 batches (thrash to L3 ~9 TB/s — the r7/r9/r10 85us wall).
// ---------------------------------------------------------------------------
__global__ __launch_bounds__(256, 2) void flash_attn(
    const bf16* __restrict__ Qd, const bf16* __restrict__ Kd,
    const bf16* __restrict__ Vt, const float* __restrict__ x,
    const float* __restrict__ gamma, float* __restrict__ out) {
  __shared__ __align__(16) bf16 Pl[2][64 * 88];
  __shared__ __align__(16) float lsum_s[64];

  int tid = threadIdx.x;
  int lane = tid & 63, w = tid >> 6;       // w = 0..3
  int lw = lane & 15, qq = lane >> 4;

  int bb, r0;
  if (gridDim.x == 256) {                  // fast path: swizzled linear grid
    int lin = blockIdx.x;
    int xcd = lin & 7;
    bb = xcd >> 1;
    r0 = (((xcd & 1) << 5) + (lin >> 3)) * 64;
  } else {                                 // staged path: per-batch
    bb = blockIdx.y;
    r0 = blockIdx.x * 64;
  }
  int chb = 64 * w;

  const bf16* Qb = Qd + ((size_t)bb << 12) * 32;
  const bf16* Kb = Kd + ((size_t)bb << 12) * 32;
  const bf16* Vb = Vt + (size_t)bb * 256 * 4096;

  bf16x8 qf = *(const bf16x8*)(Qb + (size_t)(r0 + 16 * w + lw) * 32 + qq * 8);

  f32x4 o[4][4] = {};          // [row-grp m][ch-tile t]: rows 16m+4qq+i, ch chb+16t+lw
  float l_part[4] = {};
  bf16x8 kbuf0[4], kbuf1[4], vbuf0[8], vbuf1[8];

  // ---- prologue: S(0) -> Pl[0]; prefetch K(1), V(0) ----
#pragma unroll
  for (int t = 0; t < 4; ++t)
    kbuf0[t] = *(const bf16x8*)(Kb + (size_t)(16 * t + lw) * 32 + qq * 8);
  {
    f32x4 s[4];
#pragma unroll
    for (int t = 0; t < 4; ++t) { f32x4 z = {}; s[t] = mfma16(qf, kbuf0[t], z); }
#pragma unroll
    for (int t = 0; t < 4; ++t)
#pragma unroll
      for (int i = 0; i < 4; ++i) {
        float p = __expf(s[t][i]);
        l_part[i] += p;
        Pl[0][(16 * w + 4 * qq + i) * 88 + 16 * t + lw] = (bf16)p;
      }
  }
#pragma unroll
  for (int t = 0; t < 4; ++t)
    kbuf1[t] = *(const bf16x8*)(Kb + (size_t)(64 + 16 * t + lw) * 32 + qq * 8);
#pragma unroll
  for (int t = 0; t < 4; ++t)
#pragma unroll
    for (int kc = 0; kc < 2; ++kc)
      vbuf0[t * 2 + kc] = *(const bf16x8*)(Vb + (size_t)(chb + 16 * t + lw) * 4096 + kc * 32 + qq * 8);
  __syncthreads();

#define FA_BODY(J, PCUR, PNXT, KN, KC, VC, VN)                                     \
  {                                                                                \
    const int j = (J);                                                             \
    int n1 = ((j + 1) & 63) * 64, n2 = ((j + 2) & 63) * 64;                        \
    bf16x8 af[4][2];                                                               \
    _Pragma("unroll") for (int m = 0; m < 4; ++m)                                  \
      _Pragma("unroll") for (int kc = 0; kc < 2; ++kc)                             \
        af[m][kc] = *(const bf16x8*)&Pl[PCUR][(16 * m + lw) * 88 + kc * 32 + qq * 8]; \
    if (j < 63) {                                                                  \
      f32x4 s[4];                                                                  \
      _Pragma("unroll") for (int t = 0; t < 4; ++t) {                              \
        f32x4 z = {};                                                              \
        s[t] = mfma16(qf, KN[t], z);                                               \
      }                                                                            \
      _Pragma("unroll") for (int t = 0; t < 4; ++t)                                \
        _Pragma("unroll") for (int i = 0; i < 4; ++i) {                            \
          float p = __expf(s[t][i]);                                               \
          l_part[i] += p;                                                          \
          Pl[PNXT][(16 * w + 4 * qq + i) * 88 + 16 * t + lw] = (bf16)p;            \
        }                                                                          \
      _Pragma("unroll") for (int t = 0; t < 4; ++t)                                \
        KC[t] = *(const bf16x8*)(Kb + (size_t)(n2 + 16 * t + lw) * 32 + qq * 8);   \
    }                                                                              \
    _Pragma("unroll") for (int t = 0; t < 4; ++t)                                  \
      _Pragma("unroll") for (int kc = 0; kc < 2; ++kc)                             \
        VN[t * 2 + kc] = *(const bf16x8*)(Vb + (size_t)(chb + 16 * t + lw) * 4096 + n1 + kc * 32 + qq * 8); \
    _Pragma("unroll") for (int kc = 0; kc < 2; ++kc)                               \
      _Pragma("unroll") for (int t = 0; t < 4; ++t)                                \
        _Pragma("unroll") for (int m = 0; m < 4; ++m)                              \
          o[m][t] = mfma16(af[m][kc], VC[t * 2 + kc], o[m][t]);                    \
    __syncthreads();                                                               \
  }

  for (int jj = 0; jj < 32; ++jj) {
    FA_BODY(2 * jj,     0, 1, kbuf1, kbuf0, vbuf0, vbuf1)
    FA_BODY(2 * jj + 1, 1, 0, kbuf0, kbuf1, vbuf1, vbuf0)
  }
#undef FA_BODY

  // ---- l reduction: each row's full sum lives in its wave's 16-lane group --
#pragma unroll
  for (int i = 0; i < 4; ++i) {
    float v = l_part[i];
    v += __shfl_xor(v, 1);
    v += __shfl_xor(v, 2);
    v += __shfl_xor(v, 4);
    v += __shfl_xor(v, 8);
    if (lw == 0) lsum_s[16 * w + 4 * qq + i] = v;
  }
  __syncthreads();

  float g = gamma[0];
#pragma unroll
  for (int m = 0; m < 4; ++m) {
    f32x4 lv = *(const f32x4*)&lsum_s[16 * m + 4 * qq];
#pragma unroll
    for (int i = 0; i < 4; ++i) {
      float rinv = 1.f / lv[i];
      int row = r0 + 16 * m + 4 * qq + i;
      size_t base = (((size_t)bb << 12) + row) * 256 + chb;
#pragma unroll
      for (int t = 0; t < 4; ++t)
        out[base + 16 * t + lw] = g * (o[m][t][i] * rinv) + x[base + 16 * t + lw];
    }
  }
}

extern "C" void kernel_launch(void* const* d_in, const int* in_sizes, int n_in,
                              void* d_out, int out_size, void* d_ws, size_t ws_size,
                              hipStream_t stream) {
  const float* x     = (const float*)d_in[0];
  const float* Wq    = (const float*)d_in[1];
  const float* bq    = (const float*)d_in[2];
  const float* Wk    = (const float*)d_in[3];
  const float* bk    = (const float*)d_in[4];
  const float* Wv    = (const float*)d_in[5];
  const float* bv    = (const float*)d_in[6];
  const float* gamma = (const float*)d_in[7];
  float* out = (float*)d_out;

  const size_t WT_E = 320 * 256;
  const size_t QK_E = (size_t)4096 * 32;
  const size_t VT_E = (size_t)256 * 4096;
  size_t full_bytes = (WT_E + 4 * 2 * QK_E + 4 * VT_E) * sizeof(bf16);

  bf16* Wt = (bf16*)d_ws;
  prep_wt<<<dim3(320), dim3(256), 0, stream>>>(Wq, Wk, Wv, Wt);

  if (ws_size >= full_bytes) {
    bf16* Qd = Wt + WT_E;
    bf16* Kd = Qd + 4 * QK_E;
    bf16* Vt = Kd + 4 * QK_E;
    qkv_gemm<<<dim3(256, 5), dim3(256), 0, stream>>>(x, Wt, bq, bk, bv, Qd, Kd, Vt);
    flash_attn<<<dim3(256), dim3(256), 0, stream>>>(Qd, Kd, Vt, x, gamma, out);
  } else {
    bf16* Qd = Wt + WT_E;
    bf16* Kd = Qd + QK_E;
    bf16* Vt = Kd + QK_E;
    for (int b = 0; b < 4; ++b) {
      const float* xb = x + (size_t)b * 4096 * 256;
      float* outb = out + (size_t)b * 4096 * 256;
      qkv_gemm<<<dim3(64, 5), dim3(256), 0, stream>>>(xb, Wt, bq, bk, bv, Qd, Kd, Vt);
      flash_attn<<<dim3(64, 1), dim3(256), 0, stream>>>(Qd, Kd, Vt, xb, gamma, outb);
    }
  }
}